// Round 6
// baseline (3736.224 us; speedup 1.0000x reference)
//
#include <hip/hip_runtime.h>
#include <hip/hip_bf16.h>

// BeamDecoder: greedy CVRP-style decode.
// Key identity: s_i(step) = c*( G[last,i] + (load/cap)*u_i + v_i )
//   G = (emb @ Wq[:, :H]^T) @ (emb @ Wk^T + bk)^T     [N,N]  (row = last)
//   u_i = K_i . Wq[:, H],  v_i = K_i . bq,  c = ALPHA/sqrt(H) = 0.015625
// R6: the ~2950 cyc/step chain is dominated by the 8 KB row fetch (128 cache
// lines from one wave -> suspected per-wave miss-concurrency serialization).
// Split the fetch across 8 waves (512 thr, 16 lines/wave, 1 dwordx4/lane),
// DPP partial argmax per wave, ONE barrier + double-buffered LDS merge of 8
// partials (merged redundantly by every thread). dd (visited/demand) now 4
// VGPRs/lane. Selection + score math bit-identical to R3-R5.

#define NN 2048
#define HH 1024
#define TSTEPS (NN + NN / 8)   // 2304
#define TILE 64
#define KT 16
#define DW 512                  // decode block size (8 waves)

// ---------------- pack Wq[:, :H] into ld=1024 buffer ----------------
__global__ __launch_bounds__(256) void prep_wqh(const float* __restrict__ Wq,
                                                float* __restrict__ Wqh) {
  int id = blockIdx.x * 256 + threadIdx.x;     // 0 .. 1024*1024-1
  int r = id >> 10, c = id & 1023;
  Wqh[id] = Wq[r * (HH + 2) + c];
}

// ---------------- NT GEMM: C[M,N] = A[M,K] @ B[N,K]^T (+ bias[n]) ----------------
__global__ __launch_bounds__(256) void gemm_nt(const float* __restrict__ A, int lda,
                                               const float* __restrict__ B, int ldb,
                                               float* __restrict__ C, int ldc,
                                               int K, const float* __restrict__ bias) {
  __shared__ float As[KT][TILE + 4];
  __shared__ float Bs[KT][TILE + 4];
  const int i0 = blockIdx.y * TILE;
  const int j0 = blockIdx.x * TILE;
  const int t = threadIdx.x;
  const int srow = t >> 2, sq = t & 3;
  const int tx = t & 15, ty = t >> 4;
  float acc[4][4] = {};
  for (int k0 = 0; k0 < K; k0 += KT) {
    float4 av = *(const float4*)&A[(size_t)(i0 + srow) * lda + k0 + sq * 4];
    float4 bv = *(const float4*)&B[(size_t)(j0 + srow) * ldb + k0 + sq * 4];
    __syncthreads();
    As[sq * 4 + 0][srow] = av.x; As[sq * 4 + 1][srow] = av.y;
    As[sq * 4 + 2][srow] = av.z; As[sq * 4 + 3][srow] = av.w;
    Bs[sq * 4 + 0][srow] = bv.x; Bs[sq * 4 + 1][srow] = bv.y;
    Bs[sq * 4 + 2][srow] = bv.z; Bs[sq * 4 + 3][srow] = bv.w;
    __syncthreads();
#pragma unroll
    for (int k = 0; k < KT; ++k) {
      float4 a4 = *(const float4*)&As[k][ty * 4];
      float4 b4 = *(const float4*)&Bs[k][tx * 4];
      float a[4] = {a4.x, a4.y, a4.z, a4.w};
      float b[4] = {b4.x, b4.y, b4.z, b4.w};
#pragma unroll
      for (int m = 0; m < 4; ++m)
#pragma unroll
        for (int n = 0; n < 4; ++n) acc[m][n] = fmaf(a[m], b[n], acc[m][n]);
    }
  }
  float bb[4] = {0.f, 0.f, 0.f, 0.f};
  if (bias) {
#pragma unroll
    for (int n = 0; n < 4; ++n) bb[n] = bias[j0 + tx * 4 + n];
  }
#pragma unroll
  for (int m = 0; m < 4; ++m) {
    float4 st = {acc[m][0] + bb[0], acc[m][1] + bb[1], acc[m][2] + bb[2], acc[m][3] + bb[3]};
    *(float4*)&C[(size_t)(i0 + ty * 4 + m) * ldc + j0 + tx * 4] = st;
  }
}

// ---------------- u_i = K_i . Wq[:,H], v_i = K_i . bq  (one wave per row) ---------
__global__ __launch_bounds__(64) void uv_k(const float* __restrict__ Kmat,
                                           const float* __restrict__ Wq,
                                           const float* __restrict__ bq,
                                           float* __restrict__ u, float* __restrict__ v) {
  int i = blockIdx.x;
  int lane = threadIdx.x;
  float su = 0.f, sv = 0.f;
#pragma unroll
  for (int m = 0; m < HH / 64; ++m) {
    int j = lane + 64 * m;
    float kv = Kmat[(size_t)i * HH + j];
    su = fmaf(kv, Wq[(size_t)j * (HH + 2) + HH], su);
    sv = fmaf(kv, bq[j], sv);
  }
#pragma unroll
  for (int off = 32; off; off >>= 1) {
    su += __shfl_down(su, off, 64);
    sv += __shfl_down(sv, off, 64);
  }
  if (lane == 0) { u[i] = su; v[i] = sv; }
}

// DPP-combine: merge (bv,bi) with the pair pulled through DPP ctrl CTRL.
// Invalid-source lanes get (-inf, INT_MAX) so they can never win.
#define DPP_MERGE(CTRL)                                                       \
  {                                                                           \
    int ovb = __builtin_amdgcn_update_dpp(                                    \
        (int)0xFF800000, __float_as_int(bv), (CTRL), 0xf, 0xf, false);        \
    int oib = __builtin_amdgcn_update_dpp(                                    \
        0x7fffffff, bi, (CTRL), 0xf, 0xf, false);                             \
    float ov = __int_as_float(ovb);                                           \
    if (ov > bv || (ov == bv && oib < bi)) { bv = ov; bi = oib; }             \
  }

// ---------------- sequential decode: 8 waves, 4 nodes/lane -----------------------
// Thread t owns nodes 4t..4t+3 (one float4 = wave-coalesced 1 KB slice).
// uu[4] + dd[4] (demands, +inf=visited) in VGPRs; GT row has v pre-added.
__global__ __launch_bounds__(DW, 1) void decode(const float* __restrict__ GT,
                                                const float* __restrict__ u,
                                                const float* __restrict__ demands,
                                                const int* __restrict__ capp,
                                                const int* __restrict__ depotp,
                                                float* __restrict__ out) {
  __shared__ __align__(16) float s_dem[NN];    // raw demands (for load update)
  __shared__ __align__(16) float s_drow[NN];   // GT[depot,:] cached
  __shared__ __align__(16) float s_tour[TSTEPS + 1];
  __shared__ __align__(16) float s_scr[TSTEPS];
  __shared__ float s_pv[2][8];                 // per-wave partial max (dbuf)
  __shared__ int   s_pi[2][8];                 // per-wave partial argmax

  const int t = threadIdx.x;      // 0..511 == chunk id; nodes 4t..4t+3
  const int lane = t & 63;
  const int w = t >> 6;
  const int depot = *depotp;
  const float capf = (float)(*capp);
  const float INF = __builtin_inff();
  const float NEGINF = -INF;
  const float C0 = 0.015625f;  // ALPHA / sqrt(HID), exact power of two

  for (int i = t; i < NN; i += DW) {
    s_dem[i] = demands[i];
    s_drow[i] = GT[(size_t)depot * NN + i];
  }
  if (t == 0) s_tour[0] = (float)depot;

  float4 u4 = ((const float4*)u)[t];
  float uu[4] = {u4.x, u4.y, u4.z, u4.w};
  float4 d4 = ((const float4*)demands)[t];
  float dd[4] = {d4.x, d4.y, d4.z, d4.w};
#pragma unroll
  for (int j = 0; j < 4; ++j)
    if (4 * t + j == depot) dd[j] = INF;  // depot starts visited
  __syncthreads();

  int done = 0, ntaken = 0;
  float load = capf;
  float lr = load / capf;  // same fp32 division as reference
  float4 g = ((const float4*)s_drow)[t];  // row[depot] for step 0

  for (int step = 0; step < TSTEPS; ++step) {
    if (done) {  // ref emits (depot, 0) forever once done — bulk-fill and exit
      const float df = (float)depot;
      for (int q = step + t; q < TSTEPS; q += DW) {
        s_tour[1 + q] = df;
        s_scr[q] = 0.0f;
      }
      break;
    }
    // ---- score scan over this lane's 4 nodes (g = row[last], v pre-added)
    float bv = NEGINF;
    int bi = NN;  // sentinel
    {
      float gl[4] = {g.x, g.y, g.z, g.w};
#pragma unroll
      for (int j = 0; j < 4; ++j) {
        // unscaled score: *C0 (exact 2^-6) deferred to the winner — same order
        float tt = fmaf(uu[j], lr, gl[j]);
        bool feas = (dd[j] <= load);  // +inf == visited
        if (feas && tt > bv) { bv = tt; bi = 4 * t + j; }  // ascending j: first-max
      }
    }
    // ---- per-wave argmax via DPP (result in lane 63) -> LDS partial
    DPP_MERGE(0x111);  // row_shr:1
    DPP_MERGE(0x112);  // row_shr:2
    DPP_MERGE(0x114);  // row_shr:4
    DPP_MERGE(0x118);  // row_shr:8
    DPP_MERGE(0x142);  // row_bcast:15
    DPP_MERGE(0x143);  // row_bcast:31
    const int p = step & 1;
    if (lane == 63) { s_pv[p][w] = bv; s_pi[p][w] = bi; }
    __syncthreads();
    // ---- every thread merges the 8 partials (order-free total order:
    //      max value, then smallest index — indices are distinct)
    float rbv = NEGINF;
    int rbi = NN;
#pragma unroll
    for (int k = 0; k < 8; ++k) {
      float ov = s_pv[p][k];
      int oi = s_pi[p][k];
      if (ov > rbv || (ov == rbv && oi < rbi)) { rbv = ov; rbi = oi; }
    }
    rbi = __builtin_amdgcn_readfirstlane(rbi);
    const int take = (rbv > NEGINF);
    const int nxt = __builtin_amdgcn_readfirstlane(take ? rbi : depot);

    // ---- prefetch next row FIRST: bookkeeping below hides under its latency
    if (nxt == depot) {
      g = ((const float4*)s_drow)[t];
    } else {
      g = *(const float4*)(GT + (size_t)nxt * NN + 4 * t);
    }

    // ---- state update + LDS-buffered outputs (replicated scalar state)
    if (t == 0) {
      s_tour[1 + step] = (float)nxt;
      s_scr[step] = take ? rbv * C0 : 0.0f;  // exact pow2 scale
    }
    if (take) {
      load = load - s_dem[rbi];  // broadcast LDS read; same fp32 op as reference
      ntaken++;
      if ((rbi >> 2) == t) dd[rbi & 3] = INF;  // mark visited (VGPR)
    } else {
      load = capf;
      if (ntaken == NN - 1) done = 1;  // all customers served
    }
    lr = load / capf;  // same fp32 division as reference
  }

  // ---- flush outputs
  __syncthreads();
  for (int i = t; i <= TSTEPS; i += DW) out[i] = s_tour[i];
  for (int i = t; i < TSTEPS; i += DW) out[1 + TSTEPS + i] = s_scr[i];
}

extern "C" void kernel_launch(void* const* d_in, const int* in_sizes, int n_in,
                              void* d_out, int out_size, void* d_ws, size_t ws_size,
                              hipStream_t stream) {
  const float* emb     = (const float*)d_in[0];  // [N, H]
  const float* demands = (const float*)d_in[1];  // [N]
  const float* Wq      = (const float*)d_in[2];  // [H, H+2]
  const float* bq      = (const float*)d_in[3];  // [H]
  const float* Wk      = (const float*)d_in[4];  // [H, H]
  const float* bk      = (const float*)d_in[5];  // [H]
  const int* cap       = (const int*)d_in[6];
  const int* depot     = (const int*)d_in[7];
  float* out           = (float*)d_out;          // 2305 tour + 2304 scores, fp32

  char* ws = (char*)d_ws;
  float* Kmat = (float*)(ws);                         // 8 MB  [N,H]
  float* Z    = (float*)(ws + ((size_t)8 << 20));     // 8 MB  [N,H]
  float* GT   = (float*)(ws + ((size_t)16 << 20));    // 16 MB [N,N] row=last, +v
  float* Wqh  = (float*)(ws + ((size_t)32 << 20));    // 4 MB  [H,H]
  float* u    = (float*)(ws + ((size_t)36 << 20));    // 8 KB
  float* v    = (float*)(ws + ((size_t)36 << 20) + 8192);

  hipLaunchKernelGGL(prep_wqh, dim3(4096), dim3(256), 0, stream, Wq, Wqh);
  // K = emb @ Wk^T + bk
  hipLaunchKernelGGL(gemm_nt, dim3(HH / TILE, NN / TILE), dim3(256), 0, stream,
                     emb, HH, Wk, HH, Kmat, HH, HH, bk);
  // Z = emb @ Wqh^T
  hipLaunchKernelGGL(gemm_nt, dim3(HH / TILE, NN / TILE), dim3(256), 0, stream,
                     emb, HH, Wqh, HH, Z, HH, HH, (const float*)nullptr);
  // u_i = K_i . Wq[:,H], v_i = K_i . bq   (before GT GEMM: v is its bias)
  hipLaunchKernelGGL(uv_k, dim3(NN), dim3(64), 0, stream, Kmat, Wq, bq, u, v);
  // GT = Z @ K^T + v   (GT[last, i]; v==0 here since bq==0 -> bit-identical)
  hipLaunchKernelGGL(gemm_nt, dim3(NN / TILE, NN / TILE), dim3(256), 0, stream,
                     Z, HH, Kmat, HH, GT, NN, HH, v);
  hipLaunchKernelGGL(decode, dim3(1), dim3(DW), 0, stream, GT, u, demands,
                     cap, depot, out);
}